// Round 12
// baseline (480.595 us; speedup 1.0000x reference)
//
#include <hip/hip_runtime.h>

// FeatureEnhance: 4-stream PAM + CAM + shared 3x3 conv.
// S=4, B=2, C=256, CQ=32, H=W=64, N=HW=4096.
// Round 11: flash v7 — minimal delta from validated r9: q=32 rows/wave
// (each V LDS read feeds 2 MFMA -> LDS bytes/FLOP halved), 4 waves/block,
// QBLK=128, grid stays 256 blocks. In-kernel normalization (r9 epilogue,
// both q-groups), f32 Yt, r9 transT. r10's kv-split/bf16-partial combine
// reverted (it failed with unnormalized-exp leak). All else = r9 exact.

#define HW 4096

typedef unsigned short u16;
typedef __attribute__((ext_vector_type(4))) float f32x4;
typedef __attribute__((ext_vector_type(8))) short bf16x8;
typedef __attribute__((ext_vector_type(4))) unsigned u32x4;
typedef __attribute__((ext_vector_type(8))) unsigned short u16x8;
typedef __attribute__((ext_vector_type(4))) unsigned short u16x4;

__device__ __forceinline__ float bf2f(u16 u) { return __uint_as_float(((unsigned)u) << 16); }
__device__ __forceinline__ u16 f2bf(float f) {
    unsigned x = __float_as_uint(f);
    return (u16)((x + 0x7fffu + ((x >> 16) & 1u)) >> 16);
}
__device__ __forceinline__ void gload16(const void* g, void* l) {
    __builtin_amdgcn_global_load_lds((const __attribute__((address_space(1))) void*)g,
                                     (__attribute__((address_space(3))) void*)l, 16, 0, 0);
}
__device__ __forceinline__ unsigned cvtpk(float lo, float hi) {
    unsigned r;
    asm("v_cvt_pk_bf16_f32 %0, %1, %2" : "=v"(r) : "v"(lo), "v"(hi));
    return r;
}

struct XPtrs { const float* p[4]; };

// ============ packed-K8 MFMA GEMM: C[m,n] = sum_k A[m,k]*Bpack[k,n] ============
enum { PM_QK = 0, PM_V = 1, PM_CAM = 2, PM_CONV = 3 };

template<int MODE>
__global__ __launch_bounds__(256)
void mfma_p_k(const u16* __restrict__ A, const u16* __restrict__ Bp,
              void* __restrict__ Cp,
              const float* __restrict__ b0, const float* __restrict__ b1,
              const float* __restrict__ gscale, XPtrs xs,
              int K, int lda, long aBatch, long bBatch, long cBatch, int sb0)
{
    const int n0 = blockIdx.x * 128, m0 = blockIdx.y * 128, z = blockIdx.z;
    const u16* Ab = A + (MODE == PM_CAM ? (size_t)(z & 1) * aBatch : (size_t)z * aBatch)
                      + (size_t)m0 * lda;
    const u16* Bb = Bp + (size_t)z * bBatch + (size_t)n0 * 8;

    __shared__ u16 As[4096];   // [kh][m][kl]
    __shared__ u16 Bs[4096];   // [kh][n][kl]

    const int t = threadIdx.x, lane = t & 63, w = t >> 6;
    const int mw = (w >> 1) * 64, nw = (w & 1) * 64;
    const int l15 = lane & 15, l4 = lane >> 4;

    f32x4 acc[4][4] = {};

    const u16* gaw = Ab + (size_t)lane * lda + w * 8;
    const u16* gbw = Bb + (size_t)w * (HW * 8) + (size_t)lane * 8;

    for (int kb = 0; kb < K; kb += 32) {
        gload16(gaw + kb,                    &As[w * 1024]);
        gload16(gaw + kb + (size_t)64 * lda, &As[w * 1024 + 512]);
        const u16* gb = gbw + (size_t)(kb >> 3) * (HW * 8);
        gload16(gb,       &Bs[w * 1024]);
        gload16(gb + 512, &Bs[w * 1024 + 512]);
        __syncthreads();

        bf16x8 af[4], bf[4];
        #pragma unroll
        for (int i = 0; i < 4; ++i) {
            af[i] = *(const bf16x8*)&As[l4 * 1024 + (mw + i * 16 + l15) * 8];
            bf[i] = *(const bf16x8*)&Bs[l4 * 1024 + (nw + i * 16 + l15) * 8];
        }
        #pragma unroll
        for (int mi = 0; mi < 4; ++mi)
            #pragma unroll
            for (int ni = 0; ni < 4; ++ni)
                acc[mi][ni] = __builtin_amdgcn_mfma_f32_16x16x32_bf16(af[mi], bf[ni], acc[mi][ni], 0, 0, 0);
        __syncthreads();
    }

    #pragma unroll
    for (int mi = 0; mi < 4; ++mi) {
        #pragma unroll
        for (int ni = 0; ni < 4; ++ni) {
            #pragma unroll
            for (int r = 0; r < 4; ++r) {
                const int row = m0 + mw + mi * 16 + l4 * 4 + r;
                const int col = n0 + nw + ni * 16 + l15;
                float v = acc[mi][ni][r];
                if constexpr (MODE == PM_QK) {
                    if (row < 64) {
                        v += (row < 32) ? b0[row] : b1[row - 32];
                        ((u16*)Cp)[(size_t)z * cBatch + (size_t)row * HW + col] = f2bf(v);
                    }
                } else if constexpr (MODE == PM_V) {
                    v += b0[row];
                    // packed V: Vp[(n>>3)*256 + c][n&7]  (contiguous 64KB kv-tiles)
                    ((u16*)Cp)[(size_t)z * cBatch
                               + (((size_t)(col >> 3) * 256 + row) << 3) + (col & 7)] = f2bf(v);
                } else if constexpr (MODE == PM_CAM) {
                    const float* xb = xs.p[z >> 1] + (size_t)(z & 1) * (256 * HW);
                    v = gscale[0] * v + 5.f * xb[(size_t)row * HW + col];
                    ((float*)Cp)[(size_t)z * cBatch + (size_t)row * HW + col] = v;
                } else { // PM_CONV
                    v += b0[row];
                    ((float*)Cp)[(size_t)(sb0 + z) * cBatch + (size_t)row * HW + col] = v;
                }
            }
        }
    }
}

// ============ flash v7: Yt[n][c] = gp * softmax(Q K^T) @ V^T ============
// QKt: [sb][4096][64] bf16 (cols 0-31 Q, 32-63 K). Vp: packed [kv>>3][256][8] bf16.
// 4 waves x 32 q-rows (QBLK=128). Swapped QK: lane holds S[kv][qrow=l15].
// Direct exp, in-register P via cvt_pk + ds_bpermute. Each V LDS read feeds
// 2 MFMA (two q-groups). Single 64KB V buffer, 2 barriers/iter (r9 sync).
__global__ __launch_bounds__(256)
void flash_k(const u16* __restrict__ QKt, const u16* __restrict__ Vp,
             float* __restrict__ Yt, const float* __restrict__ gscale)
{
    __shared__ u16 Vs[32768];   // 64KB V tile [g(16)][c(256)][8], linear

    const int sb = blockIdx.y;
    const int t = threadIdx.x, w = t >> 6, lane = t & 63;
    const int l15 = lane & 15, l4 = lane >> 4;
    const int q0 = blockIdx.x * 128 + w * 32;

    const u16* QKb = QKt + (size_t)sb * ((size_t)HW * 64);
    const u16* Vb  = Vp + (size_t)sb * ((size_t)256 * HW);
    float* Yb = Yt + (size_t)sb * ((size_t)HW * 256);

    // Q fragments (B operand): lane l15 = q-row, k = l4*8..
    const bf16x8 aq0 = *(const bf16x8*)&QKb[(size_t)(q0 + l15) * 64 + l4 * 8];
    const bf16x8 aq1 = *(const bf16x8*)&QKb[(size_t)(q0 + 16 + l15) * 64 + l4 * 8];

    f32x4 acc0[16] = {}, acc1[16] = {};
    float lr0 = 0.f, lr1 = 0.f;
    const f32x4 zero4 = {0.f, 0.f, 0.f, 0.f};

    // bpermute byte-indices (constant per lane)
    const int idxA = (l15 + ((lane & 16) << 1)) << 2;   // src lane l15 + 32*(l4&1)
    const int idxB = idxA + (16 << 2);
    const bool jhi = (lane & 32) != 0;                  // j-select: l4>>1

    for (int it = 0; it < 32; ++it) {
        __syncthreads();   // all waves done reading Vs from previous iteration

        // stage V tile it -> Vs (async; QK+softmax below has no LDS dependency)
        const u16* vsrc = Vb + (size_t)it * 32768;
        #pragma unroll
        for (int i = 0; i < 16; ++i)
            gload16(vsrc + i * 2048 + t * 8, &Vs[i * 2048 + t * 8]);

        // QK^T swapped + direct-exp softmax for both q-groups
        const int m0 = it * 128;
        unsigned pk0[16], pk1[16];
        float ts0 = 0.f, ts1 = 0.f;
        #pragma unroll
        for (int j = 0; j < 8; ++j) {
            const bf16x8 bk = *(const bf16x8*)&QKb[(size_t)(m0 + j * 16 + l15) * 64 + 32 + l4 * 8];
            const f32x4 s0 = __builtin_amdgcn_mfma_f32_16x16x32_bf16(bk, aq0, zero4, 0, 0, 0);
            const f32x4 s1 = __builtin_amdgcn_mfma_f32_16x16x32_bf16(bk, aq1, zero4, 0, 0, 0);
            {
                const float e0 = __expf(s0[0]), e1 = __expf(s0[1]);
                const float e2 = __expf(s0[2]), e3 = __expf(s0[3]);
                ts0 += (e0 + e1) + (e2 + e3);
                pk0[2 * j]     = cvtpk(e0, e1);
                pk0[2 * j + 1] = cvtpk(e2, e3);
            }
            {
                const float e0 = __expf(s1[0]), e1 = __expf(s1[1]);
                const float e2 = __expf(s1[2]), e3 = __expf(s1[3]);
                ts1 += (e0 + e1) + (e2 + e3);
                pk1[2 * j]     = cvtpk(e0, e1);
                pk1[2 * j + 1] = cvtpk(e2, e3);
            }
        }
        ts0 += __shfl_xor(ts0, 16); ts0 += __shfl_xor(ts0, 32); lr0 += ts0;
        ts1 += __shfl_xor(ts1, 16); ts1 += __shfl_xor(ts1, 32); lr1 += ts1;

        __syncthreads();   // stage drained (vmcnt(0) before barrier)

        // PV: in-register A fragments via bpermute; each bv read feeds 2 MFMA
        #pragma unroll
        for (int ks = 0; ks < 4; ++ks) {
            u32x4 D0, D1;
            #pragma unroll
            for (int e = 0; e < 2; ++e) {
                const unsigned a = __builtin_amdgcn_ds_bpermute(idxA, (int)pk0[4 * ks + e]);
                const unsigned b = __builtin_amdgcn_ds_bpermute(idxA, (int)pk0[4 * ks + 2 + e]);
                D0[e] = jhi ? b : a;
                const unsigned c = __builtin_amdgcn_ds_bpermute(idxB, (int)pk0[4 * ks + e]);
                const unsigned d = __builtin_amdgcn_ds_bpermute(idxB, (int)pk0[4 * ks + 2 + e]);
                D0[2 + e] = jhi ? d : c;
            }
            #pragma unroll
            for (int e = 0; e < 2; ++e) {
                const unsigned a = __builtin_amdgcn_ds_bpermute(idxA, (int)pk1[4 * ks + e]);
                const unsigned b = __builtin_amdgcn_ds_bpermute(idxA, (int)pk1[4 * ks + 2 + e]);
                D1[e] = jhi ? b : a;
                const unsigned c = __builtin_amdgcn_ds_bpermute(idxB, (int)pk1[4 * ks + e]);
                const unsigned d = __builtin_amdgcn_ds_bpermute(idxB, (int)pk1[4 * ks + 2 + e]);
                D1[2 + e] = jhi ? d : c;
            }
            const bf16x8 ap0 = __builtin_bit_cast(bf16x8, D0);
            const bf16x8 ap1 = __builtin_bit_cast(bf16x8, D1);
            #pragma unroll
            for (int ct = 0; ct < 16; ++ct) {
                const bf16x8 bv = *(const bf16x8*)&Vs[(4 * ks + l4) * 2048 + (ct * 16 + l15) * 8];
                acc0[ct] = __builtin_amdgcn_mfma_f32_16x16x32_bf16(ap0, bv, acc0[ct], 0, 0, 0);
                acc1[ct] = __builtin_amdgcn_mfma_f32_16x16x32_bf16(ap1, bv, acc1[ct], 0, 0, 0);
            }
        }
    }

    // epilogue (r9-validated): lrun keyed by l15; acc rows are l4*4+r -> bpermute
    const float gp = gscale[0];
    #pragma unroll
    for (int r = 0; r < 4; ++r) {
        const int srcl = ((lane & 48) | (l4 * 4 + r)) << 2;
        const float la = __int_as_float(__builtin_amdgcn_ds_bpermute(srcl, __float_as_int(lr0)));
        const float lb = __int_as_float(__builtin_amdgcn_ds_bpermute(srcl, __float_as_int(lr1)));
        const float sc0 = gp / la;
        const float sc1 = gp / lb;
        const int row = q0 + l4 * 4 + r;
        #pragma unroll
        for (int ct = 0; ct < 16; ++ct) {
            Yb[(size_t)row * 256 + ct * 16 + l15]        = acc0[ct][r] * sc0;
            Yb[(size_t)(row + 16) * 256 + ct * 16 + l15] = acc1[ct][r] * sc1;
        }
    }
}

// ============ X pack: X f32 [c][4096] -> Xp bf16 [c>>3][n][c&7] ============
__global__ __launch_bounds__(256)
void xpack_k(XPtrs xs, u16* __restrict__ Xp)
{
    __shared__ float tile[64][65];
    const int sb = blockIdx.z;
    const int n0 = blockIdx.x * 64, c0 = blockIdx.y * 64;
    const float* X = xs.p[sb >> 1] + (size_t)(sb & 1) * (256 * HW);
    u16* Xo = Xp + (size_t)sb * ((size_t)32 * HW * 8);
    const int t = threadIdx.x;
    {
        const int c = t >> 2, p = t & 3;
        const float4* s4 = (const float4*)&X[(size_t)(c0 + c) * HW + n0 + p * 16];
        #pragma unroll
        for (int i = 0; i < 4; ++i) {
            const float4 v = s4[i];
            tile[c][p * 16 + i * 4 + 0] = v.x;
            tile[c][p * 16 + i * 4 + 1] = v.y;
            tile[c][p * 16 + i * 4 + 2] = v.z;
            tile[c][p * 16 + i * 4 + 3] = v.w;
        }
    }
    __syncthreads();
    const int n = t >> 2;
    #pragma unroll
    for (int pp = 0; pp < 2; ++pp) {
        const int cg = (t & 3) * 2 + pp;
        u16 o[8];
        #pragma unroll
        for (int cl = 0; cl < 8; ++cl) o[cl] = f2bf(tile[cg * 8 + cl][n]);
        *(u16x8*)&Xo[(((size_t)(c0 >> 3) + cg) * HW + (n0 + n)) * 8] = *(u16x8*)o;
    }
}

// ============ bf16 transpose: QKc [64][4096] -> QKt [4096][64] per sb ============
__global__ __launch_bounds__(256)
void tqkT_k(const u16* __restrict__ src, u16* __restrict__ dst)
{
    __shared__ u16 tile[64][72];
    const int sb = blockIdx.y;
    const int n0 = blockIdx.x * 64;
    const u16* s = src + (size_t)sb * (64 * HW);
    u16* d = dst + (size_t)sb * (HW * 64);
    const int t = threadIdx.x;
    #pragma unroll
    for (int p = 0; p < 2; ++p) {
        const int c = (t >> 3) + p * 32, nn = (t & 7) * 8;
        const u16x8 v = *(const u16x8*)&s[(size_t)c * HW + n0 + nn];
        *(u16x8*)&tile[c][nn] = v;
    }
    __syncthreads();
    const int n = t >> 2, co = (t & 3) * 16;
    u16 o[16];
    #pragma unroll
    for (int j = 0; j < 16; ++j) o[j] = tile[co + j][n];
    *(u16x8*)&d[(size_t)(n0 + n) * 64 + co]     = *(u16x8*)&o[0];
    *(u16x8*)&d[(size_t)(n0 + n) * 64 + co + 8] = *(u16x8*)&o[8];
}

// ============ f32 split-K GRAM (precision-critical) ============
__global__ __launch_bounds__(256)
void gram_k(float* __restrict__ Gp, XPtrs xs)
{
    const int bx = blockIdx.x, by = blockIdx.y, bz = blockIdx.z;
    const int sbi = bz & 7;
    const int n0 = bx * 64, m0 = by * 64;
    const int t = threadIdx.x;
    const int tm = t >> 4, tn = t & 15;
    const float* xb = xs.p[sbi >> 1] + (size_t)(sbi & 1) * (256 * HW) + (bz >> 3) * 512;

    __shared__ float As[16][68];
    __shared__ float Bs[16][68];
    float acc[4][4] = {};

    for (int kb = 0; kb < 512; kb += 16) {
        {
            const int m = t >> 2, k0 = (t & 3) * 4;
            float4 v = *(const float4*)(xb + (size_t)(m0 + m) * HW + (kb + k0));
            As[k0 + 0][m] = v.x; As[k0 + 1][m] = v.y; As[k0 + 2][m] = v.z; As[k0 + 3][m] = v.w;
        }
        {
            const int n = t >> 2, k0 = (t & 3) * 4;
            float4 v = *(const float4*)(xb + (size_t)(n0 + n) * HW + (kb + k0));
            Bs[k0 + 0][n] = v.x; Bs[k0 + 1][n] = v.y; Bs[k0 + 2][n] = v.z; Bs[k0 + 3][n] = v.w;
        }
        __syncthreads();
        #pragma unroll
        for (int k = 0; k < 16; ++k) {
            const float4 a = *(const float4*)&As[k][tm * 4];
            const float4 b = *(const float4*)&Bs[k][tn * 4];
            acc[0][0] += a.x * b.x; acc[0][1] += a.x * b.y; acc[0][2] += a.x * b.z; acc[0][3] += a.x * b.w;
            acc[1][0] += a.y * b.x; acc[1][1] += a.y * b.y; acc[1][2] += a.y * b.z; acc[1][3] += a.y * b.w;
            acc[2][0] += a.z * b.x; acc[2][1] += a.z * b.y; acc[2][2] += a.z * b.z; acc[2][3] += a.z * b.w;
            acc[3][0] += a.w * b.x; acc[3][1] += a.w * b.y; acc[3][2] += a.w * b.z; acc[3][3] += a.w * b.w;
        }
        __syncthreads();
    }
    float* Cf = Gp + (size_t)bz * 65536;
    #pragma unroll
    for (int i = 0; i < 4; ++i) {
        const int m = m0 + tm * 4 + i;
        *(float4*)&Cf[(size_t)m * 256 + n0 + tn * 4] =
            make_float4(acc[i][0], acc[i][1], acc[i][2], acc[i][3]);
    }
}

__global__ __launch_bounds__(256)
void greduce_k(const float* __restrict__ Gp, float* __restrict__ G)
{
    const size_t i = (size_t)blockIdx.x * 256 + threadIdx.x;
    float s = 0.f;
    #pragma unroll
    for (int sp = 0; sp < 8; ++sp) s += Gp[(size_t)sp * 524288 + i];
    G[i] = s;
}

__global__ __launch_bounds__(256)
void cam_softmax_k(const float* __restrict__ G, float* __restrict__ attsum)
{
    __shared__ float rmn[4], rsm[4];
    const int c = blockIdx.x, b = blockIdx.y;
    const int d = threadIdx.x;
    float acc = 0.f;
    for (int s = 0; s < 4; ++s) {
        const float* row = G + (((size_t)(s * 2 + b)) * 256 + c) * 256;
        const float e = row[d];
        float mn = e;
        for (int o = 32; o; o >>= 1) mn = fminf(mn, __shfl_down(mn, o));
        if ((d & 63) == 0) rmn[d >> 6] = mn;
        __syncthreads();
        mn = fminf(fminf(rmn[0], rmn[1]), fminf(rmn[2], rmn[3]));
        const float ex = __expf(mn - e);
        float sm = ex;
        for (int o = 32; o; o >>= 1) sm += __shfl_down(sm, o);
        if ((d & 63) == 0) rsm[d >> 6] = sm;
        __syncthreads();
        sm = rsm[0] + rsm[1] + rsm[2] + rsm[3];
        acc += ex * (1.0f / sm);
        __syncthreads();
    }
    attsum[((size_t)b * 256 + c) * 256 + d] = acc;
}

// ============ transpose-add: Y[c][n] += Yt[n][c] ============
__global__ __launch_bounds__(256)
void transT_k(const float* __restrict__ Yt, float* __restrict__ Y)
{
    __shared__ float tile[64][65];
    const int sb = blockIdx.z;
    const int n0 = blockIdx.x * 64, c0 = blockIdx.y * 64;
    const float* src = Yt + (size_t)sb * ((size_t)HW * 256);
    float* dst = Y + (size_t)sb * ((size_t)256 * HW);
    const int t = threadIdx.x;
    {
        const int n = t >> 2, p = t & 3;
        const float4* s4 = (const float4*)&src[(size_t)(n0 + n) * 256 + c0 + p * 16];
        #pragma unroll
        for (int i = 0; i < 4; ++i) {
            const float4 v = s4[i];
            tile[n][p * 16 + i * 4 + 0] = v.x;
            tile[n][p * 16 + i * 4 + 1] = v.y;
            tile[n][p * 16 + i * 4 + 2] = v.z;
            tile[n][p * 16 + i * 4 + 3] = v.w;
        }
    }
    __syncthreads();
    const int c = t >> 2, p = t & 3;
    #pragma unroll
    for (int i = 0; i < 4; ++i) {
        float* dp = &dst[(size_t)(c0 + c) * HW + n0 + p * 16 + i * 4];
        float4 cur = *(float4*)dp;
        cur.x += tile[p * 16 + i * 4 + 0][c];
        cur.y += tile[p * 16 + i * 4 + 1][c];
        cur.z += tile[p * 16 + i * 4 + 2][c];
        cur.w += tile[p * 16 + i * 4 + 3][c];
        *(float4*)dp = cur;
    }
}

// ============ im2col (bf16, packed-K8): col[kg][n][kl] ============
__global__ __launch_bounds__(256)
void im2col_k(const float* __restrict__ Y, u16* __restrict__ col, int sb0)
{
    const int n = blockIdx.x * 256 + threadIdx.x;
    const int kg = blockIdx.y;
    const int sbl = blockIdx.z;
    const float* Yb = Y + (size_t)(sb0 + sbl) * ((size_t)256 * HW);
    const int h = n >> 6, wc = n & 63;
    u16 out[8];
    #pragma unroll
    for (int kl = 0; kl < 8; ++kl) {
        const int k = kg * 8 + kl;
        const int ic = k / 9, r = k - ic * 9;
        const int ih = h + r / 3 - 1, iw = wc + (r % 3) - 1;
        float v = 0.f;
        if (ih >= 0 && ih < 64 && iw >= 0 && iw < 64)
            v = Yb[(size_t)ic * HW + (ih << 6) + iw];
        out[kl] = f2bf(v);
    }
    *(u16x8*)&col[(((size_t)sbl * 288 + kg) * HW + n) * 8] = *(u16x8*)out;
}

// ============ flat f32 -> bf16 ============
__global__ __launch_bounds__(256)
void cvt_k(const float* __restrict__ s, u16* __restrict__ d)
{
    const size_t i = ((size_t)blockIdx.x * 256 + threadIdx.x) * 4;
    const float4 v = *(const float4*)&s[i];
    u16 o[4] = { f2bf(v.x), f2bf(v.y), f2bf(v.z), f2bf(v.w) };
    *(u16x4*)&d[i] = *(u16x4*)o;
}

extern "C" void kernel_launch(void* const* d_in, const int* in_sizes, int n_in,
                              void* d_out, int out_size, void* d_ws, size_t ws_size,
                              hipStream_t stream)
{
    XPtrs xs;
    xs.p[0] = (const float*)d_in[0];
    xs.p[1] = (const float*)d_in[1];
    xs.p[2] = (const float*)d_in[2];
    xs.p[3] = (const float*)d_in[3];
    const float* Wq = (const float*)d_in[4];
    const float* bq = (const float*)d_in[5];
    const float* Wk = (const float*)d_in[6];
    const float* bk = (const float*)d_in[7];
    const float* Wv = (const float*)d_in[8];
    const float* bv = (const float*)d_in[9];
    const float* gp = (const float*)d_in[10];
    const float* gc = (const float*)d_in[11];
    const float* Wd = (const float*)d_in[12];
    const float* bd = (const float*)d_in[13];

    char* base = (char*)d_ws;
    size_t off = 0;
    auto alloc = [&](size_t bytes) -> char* {
        char* p = base + off;
        off = (off + bytes + 255) & ~(size_t)255;
        return p;
    };

    // persistent through conv
    float* Y    = (float*)alloc((size_t)8 * 256 * HW * 4);      // 32 MB
    u16*   Wdh  = (u16*)  alloc((size_t)256 * 2304 * 2);        // 1.2 MB
    const size_t overlayStart = off;
    // dead before conv
    u16*   Xp   = (u16*)  alloc((size_t)8 * 32 * HW * 8 * 2);   // 16 MB
    u16*   Vp   = (u16*)  alloc((size_t)8 * 256 * HW * 2);      // 16 MB (packed kv-tiles)
    float* Yt   = (float*)alloc((size_t)8 * HW * 256 * 4);      // 32 MB
    u16*   QKc  = (u16*)  alloc((size_t)8 * 64 * HW * 2);       // 4 MB
    u16*   QKt  = (u16*)  alloc((size_t)8 * HW * 64 * 2);       // 4 MB
    float* Gp   = (float*)alloc((size_t)64 * 65536 * 4);        // 16 MB
    float* G    = (float*)alloc((size_t)8 * 65536 * 4);         // 2 MB
    float* att  = (float*)alloc((size_t)2 * 65536 * 4);         // 0.5 MB
    u16*   attH = (u16*)  alloc((size_t)2 * 65536 * 2);         // 0.25 MB
    u16*   Wqkh = (u16*)  alloc((size_t)128 * 256 * 2);         // 64 KB (rows 64-127 pad)
    u16*   Wvh  = (u16*)  alloc((size_t)256 * 256 * 2);         // 128 KB

    const size_t colPer = (size_t)288 * HW * 8 * 2;             // 18.9 MB / sb
    u16* colp = (u16*)(base + overlayStart);
    long nchunkL = (long)((ws_size - overlayStart) / colPer);
    const int nchunk = (int)(nchunkL > 8 ? 8 : (nchunkL < 1 ? 1 : nchunkL));

    dim3 T(256);

    // packs + weight converts
    xpack_k<<<dim3(64, 4, 8), T, 0, stream>>>(xs, Xp);
    cvt_k<<<dim3(8),   T, 0, stream>>>(Wq, Wqkh);
    cvt_k<<<dim3(8),   T, 0, stream>>>(Wk, Wqkh + 32 * 256);
    cvt_k<<<dim3(64),  T, 0, stream>>>(Wv, Wvh);
    cvt_k<<<dim3(576), T, 0, stream>>>(Wd, Wdh);

    // CAM attention matrix (f32 path)
    gram_k<<<dim3(4, 4, 64), T, 0, stream>>>(Gp, xs);
    greduce_k<<<dim3(2048), T, 0, stream>>>(Gp, G);
    cam_softmax_k<<<dim3(256, 2), T, 0, stream>>>(G, att);
    cvt_k<<<dim3(128), T, 0, stream>>>(att, attH);

    // projections (packed-B MFMA)
    mfma_p_k<PM_QK><<<dim3(32, 1, 8), T, 0, stream>>>(Wqkh, Xp, QKc, bq, bk, nullptr, xs,
                                                      256, 256, 0, (long)32 * HW * 8, (long)64 * HW, 0);
    tqkT_k<<<dim3(64, 8), T, 0, stream>>>(QKc, QKt);
    mfma_p_k<PM_V><<<dim3(32, 2, 8), T, 0, stream>>>(Wvh, Xp, Vp, bv, nullptr, nullptr, xs,
                                                     256, 256, 0, (long)32 * HW * 8, (long)256 * HW, 0);

    // fused flash PAM (4 waves x 32 q-rows, single-buffer V, in-kernel norm)
    flash_k<<<dim3(32, 8), dim3(256), 0, stream>>>(QKt, Vp, Yt, gp);

    // CAM apply: Y = gc * attsum[b] @ X + 5X   (packed-B MFMA)
    mfma_p_k<PM_CAM><<<dim3(32, 2, 8), T, 0, stream>>>(attH, Xp, Y, nullptr, nullptr, gc, xs,
                                                       256, 256, 65536, (long)32 * HW * 8, (long)256 * HW, 0);

    // Y += Yt^T  (PAM contribution)
    transT_k<<<dim3(64, 4, 8), T, 0, stream>>>(Yt, Y);

    // 3x3 conv: packed im2col + MFMA GEMM, chunked by ws capacity
    for (int c0 = 0; c0 < 8; c0 += nchunk) {
        const int cs = (8 - c0 < nchunk) ? (8 - c0) : nchunk;
        im2col_k<<<dim3(16, 288, cs), T, 0, stream>>>(Y, colp, c0);
        mfma_p_k<PM_CONV><<<dim3(32, 2, cs), T, 0, stream>>>(Wdh, colp, d_out, bd, nullptr, nullptr, xs,
                                                             2304, 2304, 0, (long)288 * HW * 8, (long)256 * HW, c0);
    }
}

// Round 13
// 436.171 us; speedup vs baseline: 1.1018x; 1.1018x over previous
//
#include <hip/hip_runtime.h>

// FeatureEnhance: 4-stream PAM + CAM + shared 3x3 conv.
// S=4, B=2, C=256, CQ=32, H=W=64, N=HW=4096.
// Round 12: flash reverted to r9-exact (190us, twice-validated; r11 proved
// flash is latency- not LDS-bound). NEW: Gram via split-bf16 MFMA
// (G ~= hi.hiT + hi.loT + lo.hiT, f32 acc) replacing ~100us f32 SIMT gram.
// xpack emits packed XpG hi/lo from its existing tile. XpG aliased with Vp.

#define HW 4096

typedef unsigned short u16;
typedef __attribute__((ext_vector_type(4))) float f32x4;
typedef __attribute__((ext_vector_type(8))) short bf16x8;
typedef __attribute__((ext_vector_type(4))) unsigned u32x4;
typedef __attribute__((ext_vector_type(8))) unsigned short u16x8;
typedef __attribute__((ext_vector_type(4))) unsigned short u16x4;

__device__ __forceinline__ float bf2f(u16 u) { return __uint_as_float(((unsigned)u) << 16); }
__device__ __forceinline__ u16 f2bf(float f) {
    unsigned x = __float_as_uint(f);
    return (u16)((x + 0x7fffu + ((x >> 16) & 1u)) >> 16);
}
__device__ __forceinline__ void gload16(const void* g, void* l) {
    __builtin_amdgcn_global_load_lds((const __attribute__((address_space(1))) void*)g,
                                     (__attribute__((address_space(3))) void*)l, 16, 0, 0);
}
__device__ __forceinline__ unsigned cvtpk(float lo, float hi) {
    unsigned r;
    asm("v_cvt_pk_bf16_f32 %0, %1, %2" : "=v"(r) : "v"(lo), "v"(hi));
    return r;
}

struct XPtrs { const float* p[4]; };

// ============ packed-K8 MFMA GEMM: C[m,n] = sum_k A[m,k]*Bpack[k,n] ============
enum { PM_QK = 0, PM_V = 1, PM_CAM = 2, PM_CONV = 3 };

template<int MODE>
__global__ __launch_bounds__(256)
void mfma_p_k(const u16* __restrict__ A, const u16* __restrict__ Bp,
              void* __restrict__ Cp,
              const float* __restrict__ b0, const float* __restrict__ b1,
              const float* __restrict__ gscale, XPtrs xs,
              int K, int lda, long aBatch, long bBatch, long cBatch, int sb0)
{
    const int n0 = blockIdx.x * 128, m0 = blockIdx.y * 128, z = blockIdx.z;
    const u16* Ab = A + (MODE == PM_CAM ? (size_t)(z & 1) * aBatch : (size_t)z * aBatch)
                      + (size_t)m0 * lda;
    const u16* Bb = Bp + (size_t)z * bBatch + (size_t)n0 * 8;

    __shared__ u16 As[4096];   // [kh][m][kl]
    __shared__ u16 Bs[4096];   // [kh][n][kl]

    const int t = threadIdx.x, lane = t & 63, w = t >> 6;
    const int mw = (w >> 1) * 64, nw = (w & 1) * 64;
    const int l15 = lane & 15, l4 = lane >> 4;

    f32x4 acc[4][4] = {};

    const u16* gaw = Ab + (size_t)lane * lda + w * 8;
    const u16* gbw = Bb + (size_t)w * (HW * 8) + (size_t)lane * 8;

    for (int kb = 0; kb < K; kb += 32) {
        gload16(gaw + kb,                    &As[w * 1024]);
        gload16(gaw + kb + (size_t)64 * lda, &As[w * 1024 + 512]);
        const u16* gb = gbw + (size_t)(kb >> 3) * (HW * 8);
        gload16(gb,       &Bs[w * 1024]);
        gload16(gb + 512, &Bs[w * 1024 + 512]);
        __syncthreads();

        bf16x8 af[4], bf[4];
        #pragma unroll
        for (int i = 0; i < 4; ++i) {
            af[i] = *(const bf16x8*)&As[l4 * 1024 + (mw + i * 16 + l15) * 8];
            bf[i] = *(const bf16x8*)&Bs[l4 * 1024 + (nw + i * 16 + l15) * 8];
        }
        #pragma unroll
        for (int mi = 0; mi < 4; ++mi)
            #pragma unroll
            for (int ni = 0; ni < 4; ++ni)
                acc[mi][ni] = __builtin_amdgcn_mfma_f32_16x16x32_bf16(af[mi], bf[ni], acc[mi][ni], 0, 0, 0);
        __syncthreads();
    }

    #pragma unroll
    for (int mi = 0; mi < 4; ++mi) {
        #pragma unroll
        for (int ni = 0; ni < 4; ++ni) {
            #pragma unroll
            for (int r = 0; r < 4; ++r) {
                const int row = m0 + mw + mi * 16 + l4 * 4 + r;
                const int col = n0 + nw + ni * 16 + l15;
                float v = acc[mi][ni][r];
                if constexpr (MODE == PM_QK) {
                    if (row < 64) {
                        v += (row < 32) ? b0[row] : b1[row - 32];
                        ((u16*)Cp)[(size_t)z * cBatch + (size_t)row * HW + col] = f2bf(v);
                    }
                } else if constexpr (MODE == PM_V) {
                    v += b0[row];
                    // packed V: Vp[(n>>3)*256 + c][n&7]  (contiguous 64KB kv-tiles)
                    ((u16*)Cp)[(size_t)z * cBatch
                               + (((size_t)(col >> 3) * 256 + row) << 3) + (col & 7)] = f2bf(v);
                } else if constexpr (MODE == PM_CAM) {
                    const float* xb = xs.p[z >> 1] + (size_t)(z & 1) * (256 * HW);
                    v = gscale[0] * v + 5.f * xb[(size_t)row * HW + col];
                    ((float*)Cp)[(size_t)z * cBatch + (size_t)row * HW + col] = v;
                } else { // PM_CONV
                    v += b0[row];
                    ((float*)Cp)[(size_t)(sb0 + z) * cBatch + (size_t)row * HW + col] = v;
                }
            }
        }
    }
}

// ============ split-bf16 MFMA Gram: Gp[bz] = X[m,:k-slice] . X[n,:k-slice]^T ============
// XpG hi/lo: per sb [512 kg][256 ch][8] bf16 (packed-K8; serves A and B).
// G ~= hi.hiT + hi.loT + lo.hiT (f32 accumulate). grid (2,2,64): bz = sp*8+sb.
__global__ __launch_bounds__(256)
void gramm_k(const u16* __restrict__ Hi, const u16* __restrict__ Lo,
             float* __restrict__ Gp)
{
    const int n0 = blockIdx.x * 128, m0 = blockIdx.y * 128, bz = blockIdx.z;
    const int sb = bz & 7, sp = bz >> 3;
    const u16* Hb = Hi + (size_t)sb * 1048576;
    const u16* Lb = Lo + (size_t)sb * 1048576;

    __shared__ u16 AsH[4096], AsL[4096], BsH[4096], BsL[4096];

    const int t = threadIdx.x, lane = t & 63, w = t >> 6;
    const int mw = (w >> 1) * 64, nw = (w & 1) * 64;
    const int l15 = lane & 15, l4 = lane >> 4;

    f32x4 acc[4][4] = {};

    for (int kb = sp * 512; kb < sp * 512 + 512; kb += 32) {
        const size_t g = (size_t)(kb >> 3) + w;   // this wave's k-group
        const u16* hA = Hb + g * 2048 + (size_t)(m0 + lane) * 8;
        const u16* lA = Lb + g * 2048 + (size_t)(m0 + lane) * 8;
        const u16* hB = Hb + g * 2048 + (size_t)(n0 + lane) * 8;
        const u16* lB = Lb + g * 2048 + (size_t)(n0 + lane) * 8;
        gload16(hA,       &AsH[w * 1024]);
        gload16(hA + 512, &AsH[w * 1024 + 512]);
        gload16(lA,       &AsL[w * 1024]);
        gload16(lA + 512, &AsL[w * 1024 + 512]);
        gload16(hB,       &BsH[w * 1024]);
        gload16(hB + 512, &BsH[w * 1024 + 512]);
        gload16(lB,       &BsL[w * 1024]);
        gload16(lB + 512, &BsL[w * 1024 + 512]);
        __syncthreads();

        bf16x8 ah[4], al[4], bh[4], bl[4];
        #pragma unroll
        for (int i = 0; i < 4; ++i) {
            ah[i] = *(const bf16x8*)&AsH[l4 * 1024 + (mw + i * 16 + l15) * 8];
            al[i] = *(const bf16x8*)&AsL[l4 * 1024 + (mw + i * 16 + l15) * 8];
            bh[i] = *(const bf16x8*)&BsH[l4 * 1024 + (nw + i * 16 + l15) * 8];
            bl[i] = *(const bf16x8*)&BsL[l4 * 1024 + (nw + i * 16 + l15) * 8];
        }
        #pragma unroll
        for (int mi = 0; mi < 4; ++mi)
            #pragma unroll
            for (int ni = 0; ni < 4; ++ni) {
                acc[mi][ni] = __builtin_amdgcn_mfma_f32_16x16x32_bf16(ah[mi], bh[ni], acc[mi][ni], 0, 0, 0);
                acc[mi][ni] = __builtin_amdgcn_mfma_f32_16x16x32_bf16(ah[mi], bl[ni], acc[mi][ni], 0, 0, 0);
                acc[mi][ni] = __builtin_amdgcn_mfma_f32_16x16x32_bf16(al[mi], bh[ni], acc[mi][ni], 0, 0, 0);
            }
        __syncthreads();
    }

    float* Cf = Gp + (size_t)bz * 65536;
    #pragma unroll
    for (int mi = 0; mi < 4; ++mi)
        #pragma unroll
        for (int ni = 0; ni < 4; ++ni)
            #pragma unroll
            for (int r = 0; r < 4; ++r) {
                const int row = m0 + mw + mi * 16 + l4 * 4 + r;
                const int col = n0 + nw + ni * 16 + l15;
                Cf[(size_t)row * 256 + col] = acc[mi][ni][r];
            }
}

// ============ flash (r9-exact, twice-validated): Yt[n][c] = gp*softmax(QK^T)@V^T ============
__global__ __launch_bounds__(512, 4)
void flash_k(const u16* __restrict__ QKt, const u16* __restrict__ Vp,
             float* __restrict__ Yt, const float* __restrict__ gscale)
{
    __shared__ u16 Vs[32768];   // 64KB V tile [g(16)][c(256)][8], linear

    const int sb = blockIdx.y;
    const int t = threadIdx.x, w = t >> 6, lane = t & 63;
    const int l15 = lane & 15, l4 = lane >> 4;
    const int q0 = blockIdx.x * 128 + w * 16;

    const u16* QKb = QKt + (size_t)sb * ((size_t)HW * 64);
    const u16* Vb  = Vp + (size_t)sb * ((size_t)256 * HW);
    float* Yb = Yt + (size_t)sb * ((size_t)HW * 256);

    const bf16x8 aq = *(const bf16x8*)&QKb[(size_t)(q0 + l15) * 64 + l4 * 8];

    f32x4 acc[16] = {};
    float lrun = 0.f;
    const f32x4 zero4 = {0.f, 0.f, 0.f, 0.f};

    const int idxA = (l15 + ((lane & 16) << 1)) << 2;
    const int idxB = idxA + (16 << 2);
    const bool jhi = (lane & 32) != 0;

    for (int it = 0; it < 32; ++it) {
        __syncthreads();

        const u16* vsrc = Vb + (size_t)it * 32768;
        #pragma unroll
        for (int i = 0; i < 8; ++i)
            gload16(vsrc + i * 4096 + t * 8, &Vs[i * 4096 + t * 8]);

        const int m0 = it * 128;
        unsigned pk[16];
        float tsum = 0.f;
        #pragma unroll
        for (int j = 0; j < 8; ++j) {
            const bf16x8 bk = *(const bf16x8*)&QKb[(size_t)(m0 + j * 16 + l15) * 64 + 32 + l4 * 8];
            const f32x4 sj = __builtin_amdgcn_mfma_f32_16x16x32_bf16(bk, aq, zero4, 0, 0, 0);
            const float e0 = __expf(sj[0]);
            const float e1 = __expf(sj[1]);
            const float e2 = __expf(sj[2]);
            const float e3 = __expf(sj[3]);
            tsum += (e0 + e1) + (e2 + e3);
            pk[2 * j]     = cvtpk(e0, e1);
            pk[2 * j + 1] = cvtpk(e2, e3);
        }
        tsum += __shfl_xor(tsum, 16);
        tsum += __shfl_xor(tsum, 32);
        lrun += tsum;

        __syncthreads();

        #pragma unroll
        for (int ks = 0; ks < 4; ++ks) {
            u32x4 D;
            {
                const unsigned a0 = __builtin_amdgcn_ds_bpermute(idxA, (int)pk[4 * ks + 0]);
                const unsigned b0_ = __builtin_amdgcn_ds_bpermute(idxA, (int)pk[4 * ks + 2]);
                D[0] = jhi ? b0_ : a0;
                const unsigned a1 = __builtin_amdgcn_ds_bpermute(idxA, (int)pk[4 * ks + 1]);
                const unsigned b1_ = __builtin_amdgcn_ds_bpermute(idxA, (int)pk[4 * ks + 3]);
                D[1] = jhi ? b1_ : a1;
                const unsigned a2 = __builtin_amdgcn_ds_bpermute(idxB, (int)pk[4 * ks + 0]);
                const unsigned b2_ = __builtin_amdgcn_ds_bpermute(idxB, (int)pk[4 * ks + 2]);
                D[2] = jhi ? b2_ : a2;
                const unsigned a3 = __builtin_amdgcn_ds_bpermute(idxB, (int)pk[4 * ks + 1]);
                const unsigned b3_ = __builtin_amdgcn_ds_bpermute(idxB, (int)pk[4 * ks + 3]);
                D[3] = jhi ? b3_ : a3;
            }
            const bf16x8 ap = __builtin_bit_cast(bf16x8, D);
            #pragma unroll
            for (int ct = 0; ct < 16; ++ct) {
                const bf16x8 bv = *(const bf16x8*)&Vs[(4 * ks + l4) * 2048 + (ct * 16 + l15) * 8];
                acc[ct] = __builtin_amdgcn_mfma_f32_16x16x32_bf16(ap, bv, acc[ct], 0, 0, 0);
            }
        }
    }

    const float gp = gscale[0];
    #pragma unroll
    for (int r = 0; r < 4; ++r) {
        const int srcl = ((lane & 48) | (l4 * 4 + r)) << 2;
        const float lr = __int_as_float(__builtin_amdgcn_ds_bpermute(srcl, __float_as_int(lrun)));
        const float sc = gp / lr;
        const int row = q0 + l4 * 4 + r;
        #pragma unroll
        for (int ct = 0; ct < 16; ++ct)
            Yb[(size_t)row * 256 + ct * 16 + l15] = acc[ct][r] * sc;
    }
}

// ============ X pack: Xp [c>>3][n][c&7]  +  XpG hi/lo [n>>3][c][n&7] ============
__global__ __launch_bounds__(256)
void xpack_k(XPtrs xs, u16* __restrict__ Xp,
             u16* __restrict__ XpGhi, u16* __restrict__ XpGlo)
{
    __shared__ float tile[64][65];
    const int sb = blockIdx.z;
    const int n0 = blockIdx.x * 64, c0 = blockIdx.y * 64;
    const float* X = xs.p[sb >> 1] + (size_t)(sb & 1) * (256 * HW);
    u16* Xo = Xp + (size_t)sb * ((size_t)32 * HW * 8);
    const int t = threadIdx.x;
    {
        const int c = t >> 2, p = t & 3;
        const float4* s4 = (const float4*)&X[(size_t)(c0 + c) * HW + n0 + p * 16];
        #pragma unroll
        for (int i = 0; i < 4; ++i) {
            const float4 v = s4[i];
            tile[c][p * 16 + i * 4 + 0] = v.x;
            tile[c][p * 16 + i * 4 + 1] = v.y;
            tile[c][p * 16 + i * 4 + 2] = v.z;
            tile[c][p * 16 + i * 4 + 3] = v.w;
        }
    }
    __syncthreads();
    // phase 1: packed-channel Xp
    {
        const int n = t >> 2;
        #pragma unroll
        for (int pp = 0; pp < 2; ++pp) {
            const int cg = (t & 3) * 2 + pp;
            u16 o[8];
            #pragma unroll
            for (int cl = 0; cl < 8; ++cl) o[cl] = f2bf(tile[cg * 8 + cl][n]);
            *(u16x8*)&Xo[(((size_t)(c0 >> 3) + cg) * HW + (n0 + n)) * 8] = *(u16x8*)o;
        }
    }
    // phase 2: packed-spatial XpG hi/lo (for gramm)
    {
        const int cl = t & 63, kgl = t >> 6;
        u16* Hb = XpGhi + (size_t)sb * 1048576;
        u16* Lb = XpGlo + (size_t)sb * 1048576;
        #pragma unroll
        for (int q = 0; q < 2; ++q) {
            const int kg = kgl + q * 4;
            u16 hi8[8], lo8[8];
            #pragma unroll
            for (int j = 0; j < 8; ++j) {
                const float v = tile[cl][kg * 8 + j];
                const u16 h = f2bf(v);
                hi8[j] = h;
                lo8[j] = f2bf(v - bf2f(h));
            }
            const size_t o = (((size_t)(n0 >> 3) + kg) * 256 + (c0 + cl)) * 8;
            *(u16x8*)&Hb[o] = *(u16x8*)hi8;
            *(u16x8*)&Lb[o] = *(u16x8*)lo8;
        }
    }
}

// ============ bf16 transpose: QKc [64][4096] -> QKt [4096][64] per sb ============
__global__ __launch_bounds__(256)
void tqkT_k(const u16* __restrict__ src, u16* __restrict__ dst)
{
    __shared__ u16 tile[64][72];
    const int sb = blockIdx.y;
    const int n0 = blockIdx.x * 64;
    const u16* s = src + (size_t)sb * (64 * HW);
    u16* d = dst + (size_t)sb * (HW * 64);
    const int t = threadIdx.x;
    #pragma unroll
    for (int p = 0; p < 2; ++p) {
        const int c = (t >> 3) + p * 32, nn = (t & 7) * 8;
        const u16x8 v = *(const u16x8*)&s[(size_t)c * HW + n0 + nn];
        *(u16x8*)&tile[c][nn] = v;
    }
    __syncthreads();
    const int n = t >> 2, co = (t & 3) * 16;
    u16 o[16];
    #pragma unroll
    for (int j = 0; j < 16; ++j) o[j] = tile[co + j][n];
    *(u16x8*)&d[(size_t)(n0 + n) * 64 + co]     = *(u16x8*)&o[0];
    *(u16x8*)&d[(size_t)(n0 + n) * 64 + co + 8] = *(u16x8*)&o[8];
}

__global__ __launch_bounds__(256)
void greduce_k(const float* __restrict__ Gp, float* __restrict__ G)
{
    const size_t i = (size_t)blockIdx.x * 256 + threadIdx.x;
    float s = 0.f;
    #pragma unroll
    for (int sp = 0; sp < 8; ++sp) s += Gp[(size_t)sp * 524288 + i];
    G[i] = s;
}

__global__ __launch_bounds__(256)
void cam_softmax_k(const float* __restrict__ G, float* __restrict__ attsum)
{
    __shared__ float rmn[4], rsm[4];
    const int c = blockIdx.x, b = blockIdx.y;
    const int d = threadIdx.x;
    float acc = 0.f;
    for (int s = 0; s < 4; ++s) {
        const float* row = G + (((size_t)(s * 2 + b)) * 256 + c) * 256;
        const float e = row[d];
        float mn = e;
        for (int o = 32; o; o >>= 1) mn = fminf(mn, __shfl_down(mn, o));
        if ((d & 63) == 0) rmn[d >> 6] = mn;
        __syncthreads();
        mn = fminf(fminf(rmn[0], rmn[1]), fminf(rmn[2], rmn[3]));
        const float ex = __expf(mn - e);
        float sm = ex;
        for (int o = 32; o; o >>= 1) sm += __shfl_down(sm, o);
        if ((d & 63) == 0) rsm[d >> 6] = sm;
        __syncthreads();
        sm = rsm[0] + rsm[1] + rsm[2] + rsm[3];
        acc += ex * (1.0f / sm);
        __syncthreads();
    }
    attsum[((size_t)b * 256 + c) * 256 + d] = acc;
}

// ============ transpose-add: Y[c][n] += Yt[n][c] ============
__global__ __launch_bounds__(256)
void transT_k(const float* __restrict__ Yt, float* __restrict__ Y)
{
    __shared__ float tile[64][65];
    const int sb = blockIdx.z;
    const int n0 = blockIdx.x * 64, c0 = blockIdx.y * 64;
    const float* src = Yt + (size_t)sb * ((size_t)HW * 256);
    float* dst = Y + (size_t)sb * ((size_t)256 * HW);
    const int t = threadIdx.x;
    {
        const int n = t >> 2, p = t & 3;
        const float4* s4 = (const float4*)&src[(size_t)(n0 + n) * 256 + c0 + p * 16];
        #pragma unroll
        for (int i = 0; i < 4; ++i) {
            const float4 v = s4[i];
            tile[n][p * 16 + i * 4 + 0] = v.x;
            tile[n][p * 16 + i * 4 + 1] = v.y;
            tile[n][p * 16 + i * 4 + 2] = v.z;
            tile[n][p * 16 + i * 4 + 3] = v.w;
        }
    }
    __syncthreads();
    const int c = t >> 2, p = t & 3;
    #pragma unroll
    for (int i = 0; i < 4; ++i) {
        float* dp = &dst[(size_t)(c0 + c) * HW + n0 + p * 16 + i * 4];
        float4 cur = *(float4*)dp;
        cur.x += tile[p * 16 + i * 4 + 0][c];
        cur.y += tile[p * 16 + i * 4 + 1][c];
        cur.z += tile[p * 16 + i * 4 + 2][c];
        cur.w += tile[p * 16 + i * 4 + 3][c];
        *(float4*)dp = cur;
    }
}

// ============ im2col (bf16, packed-K8): col[kg][n][kl] ============
__global__ __launch_bounds__(256)
void im2col_k(const float* __restrict__ Y, u16* __restrict__ col, int sb0)
{
    const int n = blockIdx.x * 256 + threadIdx.x;
    const int kg = blockIdx.y;
    const int sbl = blockIdx.z;
    const float* Yb = Y + (size_t)(sb0 + sbl) * ((size_t)256 * HW);
    const int h = n >> 6, wc = n & 63;
    u16 out[8];
    #pragma unroll
    for (int kl = 0; kl < 8; ++kl) {
        const int k = kg * 8 + kl;
        const int ic = k / 9, r = k - ic * 9;
        const int ih = h + r / 3 - 1, iw = wc + (r % 3) - 1;
        float v = 0.f;
        if (ih >= 0 && ih < 64 && iw >= 0 && iw < 64)
            v = Yb[(size_t)ic * HW + (ih << 6) + iw];
        out[kl] = f2bf(v);
    }
    *(u16x8*)&col[(((size_t)sbl * 288 + kg) * HW + n) * 8] = *(u16x8*)out;
}

// ============ flat f32 -> bf16 ============
__global__ __launch_bounds__(256)
void cvt_k(const float* __restrict__ s, u16* __restrict__ d)
{
    const size_t i = ((size_t)blockIdx.x * 256 + threadIdx.x) * 4;
    const float4 v = *(const float4*)&s[i];
    u16 o[4] = { f2bf(v.x), f2bf(v.y), f2bf(v.z), f2bf(v.w) };
    *(u16x4*)&d[i] = *(u16x4*)o;
}

extern "C" void kernel_launch(void* const* d_in, const int* in_sizes, int n_in,
                              void* d_out, int out_size, void* d_ws, size_t ws_size,
                              hipStream_t stream)
{
    XPtrs xs;
    xs.p[0] = (const float*)d_in[0];
    xs.p[1] = (const float*)d_in[1];
    xs.p[2] = (const float*)d_in[2];
    xs.p[3] = (const float*)d_in[3];
    const float* Wq = (const float*)d_in[4];
    const float* bq = (const float*)d_in[5];
    const float* Wk = (const float*)d_in[6];
    const float* bk = (const float*)d_in[7];
    const float* Wv = (const float*)d_in[8];
    const float* bv = (const float*)d_in[9];
    const float* gp = (const float*)d_in[10];
    const float* gc = (const float*)d_in[11];
    const float* Wd = (const float*)d_in[12];
    const float* bd = (const float*)d_in[13];

    char* base = (char*)d_ws;
    size_t off = 0;
    auto alloc = [&](size_t bytes) -> char* {
        char* p = base + off;
        off = (off + bytes + 255) & ~(size_t)255;
        return p;
    };

    // persistent through conv
    float* Y    = (float*)alloc((size_t)8 * 256 * HW * 4);      // 32 MB
    u16*   Wdh  = (u16*)  alloc((size_t)256 * 2304 * 2);        // 1.2 MB
    const size_t overlayStart = off;
    // dead before conv
    u16*   Xp   = (u16*)  alloc((size_t)8 * 32 * HW * 8 * 2);   // 16 MB
    float* Gp   = (float*)alloc((size_t)64 * 65536 * 4);        // 16 MB
    float* G    = (float*)alloc((size_t)8 * 65536 * 4);         // 2 MB
    float* att  = (float*)alloc((size_t)2 * 65536 * 4);         // 0.5 MB
    u16*   attH = (u16*)  alloc((size_t)2 * 65536 * 2);         // 0.25 MB
    float* Yt   = (float*)alloc((size_t)8 * HW * 256 * 4);      // 32 MB
    u16*   QKc  = (u16*)  alloc((size_t)8 * 64 * HW * 2);       // 4 MB
    u16*   QKt  = (u16*)  alloc((size_t)8 * HW * 64 * 2);       // 4 MB
    u16*   Wqkh = (u16*)  alloc((size_t)128 * 256 * 2);         // 64 KB
    u16*   Wvh  = (u16*)  alloc((size_t)256 * 256 * 2);         // 128 KB
    // shared region: XpG hi/lo (32MB) until gramm; then Vp (16MB)
    u16*   XpGhi = (u16*) alloc((size_t)8 * 1048576 * 2);       // 16 MB
    u16*   XpGlo = (u16*) alloc((size_t)8 * 1048576 * 2);       // 16 MB
    u16*   Vp    = XpGhi;                                       // alias (XpG dead post-gramm)
    // total ~142 MB

    const size_t colPer = (size_t)288 * HW * 8 * 2;             // 18.9 MB / sb
    u16* colp = (u16*)(base + overlayStart);
    long nchunkL = (long)((ws_size - overlayStart) / colPer);
    const int nchunk = (int)(nchunkL > 8 ? 8 : (nchunkL < 1 ? 1 : nchunkL));

    dim3 T(256);

    // packs + weight converts
    xpack_k<<<dim3(64, 4, 8), T, 0, stream>>>(xs, Xp, XpGhi, XpGlo);
    cvt_k<<<dim3(8),   T, 0, stream>>>(Wq, Wqkh);
    cvt_k<<<dim3(8),   T, 0, stream>>>(Wk, Wqkh + 32 * 256);
    cvt_k<<<dim3(64),  T, 0, stream>>>(Wv, Wvh);
    cvt_k<<<dim3(576), T, 0, stream>>>(Wd, Wdh);

    // CAM attention matrix: split-bf16 MFMA gram -> reduce -> softmax-sum
    gramm_k<<<dim3(2, 2, 64), T, 0, stream>>>(XpGhi, XpGlo, Gp);
    greduce_k<<<dim3(2048), T, 0, stream>>>(Gp, G);
    cam_softmax_k<<<dim3(256, 2), T, 0, stream>>>(G, att);
    cvt_k<<<dim3(128), T, 0, stream>>>(att, attH);

    // projections (packed-B MFMA). PM_V runs after gramm -> Vp may alias XpGhi.
    mfma_p_k<PM_QK><<<dim3(32, 1, 8), T, 0, stream>>>(Wqkh, Xp, QKc, bq, bk, nullptr, xs,
                                                      256, 256, 0, (long)32 * HW * 8, (long)64 * HW, 0);
    tqkT_k<<<dim3(64, 8), T, 0, stream>>>(QKc, QKt);
    mfma_p_k<PM_V><<<dim3(32, 2, 8), T, 0, stream>>>(Wvh, Xp, Vp, bv, nullptr, nullptr, xs,
                                                     256, 256, 0, (long)32 * HW * 8, (long)256 * HW, 0);

    // fused flash PAM (r9-exact)
    flash_k<<<dim3(32, 8), dim3(512), 0, stream>>>(QKt, Vp, Yt, gp);

    // CAM apply: Y = gc * attsum[b] @ X + 5X   (packed-B MFMA)
    mfma_p_k<PM_CAM><<<dim3(32, 2, 8), T, 0, stream>>>(attH, Xp, Y, nullptr, nullptr, gc, xs,
                                                       256, 256, 65536, (long)32 * HW * 8, (long)256 * HW, 0);

    // Y += Yt^T  (PAM contribution)
    transT_k<<<dim3(64, 4, 8), T, 0, stream>>>(Yt, Y);

    // 3x3 conv: packed im2col + MFMA GEMM, chunked by ws capacity
    for (int c0 = 0; c0 < 8; c0 += nchunk) {
        const int cs = (8 - c0 < nchunk) ? (8 - c0) : nchunk;
        im2col_k<<<dim3(16, 288, cs), T, 0, stream>>>(Y, colp, c0);
        mfma_p_k<PM_CONV><<<dim3(32, 2, cs), T, 0, stream>>>(Wdh, colp, d_out, bd, nullptr, nullptr, xs,
                                                             2304, 2304, 0, (long)288 * HW * 8, (long)256 * HW, c0);
    }
}